// Round 1
// baseline (134.681 us; speedup 1.0000x reference)
//
#include <hip/hip_runtime.h>

// Problem constants (from setup_inputs): B=32, S=524288, HOP=256, L=100.
constexpr int HOP    = 256;
constexpr int L      = 100;
constexpr int FRAMES = 2048;   // S / HOP
constexpr int B      = 32;
constexpr int FPB    = 4;      // frames handled per block (256 thr * 4 elem = 1024 = 4*HOP)

// One block handles 4 consecutive frames of one batch row.
// LDS holds, for each of the 4 frames, the interleaved (floor_row, ceil_row)
// pair table (L+1 entries incl. wrap column) so every element's 2x2 bilinear
// gather is two aligned ds_read_b64's.
__global__ __launch_bounds__(256) void glottal_kernel(
    const float* __restrict__ wp,
    const float* __restrict__ tables,
    float* __restrict__ out)
{
    __shared__ float2 pairs[FPB][L + 1];

    const int tid = threadIdx.x;
    const int b   = blockIdx.x >> 9;      // / (FRAMES/FPB) = 512
    const int g   = blockIdx.x & 511;
    const int f0  = g * FPB;

    const float* trow = tables + ((size_t)b * (FRAMES + 1) + (size_t)f0) * L;

    // Stage FPB interleaved row-pairs: pairs[r][c] = (tables[f0+r][c], tables[f0+r+1][c]),
    // with c==L wrapping to column 0 (the reference's padded wrap column).
    for (int i = tid; i < FPB * (L + 1); i += 256) {
        int r  = i / (L + 1);
        int c  = i - r * (L + 1);
        int cs = (c == L) ? 0 : c;
        pairs[r][c] = make_float2(trow[r * L + cs], trow[(r + 1) * L + cs]);
    }
    __syncthreads();

    // Each thread: 4 consecutive elements (float4) within one frame.
    const size_t base = ((size_t)b * FRAMES + (size_t)f0) * HOP + (size_t)tid * 4;
    float4 w = *reinterpret_cast<const float4*>(wp + base);

    const float2* row = pairs[tid >> 6];   // relative frame = tid/64 (wave-uniform)
    const int h0 = (tid & 63) * 4;         // position within hop

    float wv[4] = {w.x, w.y, w.z, w.w};
    float res[4];
#pragma unroll
    for (int j = 0; j < 4; ++j) {
        float idx_raw = wv[j] * (float)L;
        int fi = (int)idx_raw;                       // trunc toward zero, wp >= 0
        fi = fi < 0 ? 0 : (fi > L - 1 ? L - 1 : fi); // clip like reference
        float p  = idx_raw - (float)fi;
        float2 lo = row[fi];       // (floor_flow[fi],   ceil_flow[fi])
        float2 hi = row[fi + 1];   // (floor_flow[fi+1], ceil_flow[fi+1])
        float sf = lo.x + (hi.x - lo.x) * p;   // sel_floor
        float sc = lo.y + (hi.y - lo.y) * p;   // sel_ceil
        float p2 = (float)(h0 + j) * (1.0f / HOP);
        res[j] = sf + (sc - sf) * p2;
    }

    *reinterpret_cast<float4*>(out + base) = make_float4(res[0], res[1], res[2], res[3]);
}

extern "C" void kernel_launch(void* const* d_in, const int* in_sizes, int n_in,
                              void* d_out, int out_size, void* d_ws, size_t ws_size,
                              hipStream_t stream) {
    const float* wp     = (const float*)d_in[0];
    const float* tables = (const float*)d_in[1];
    // d_in[2] is hop_length (scalar int) — baked in as constexpr HOP.
    float* out = (float*)d_out;

    dim3 grid(B * (FRAMES / FPB));   // 32 * 512 = 16384 blocks
    glottal_kernel<<<grid, 256, 0, stream>>>(wp, tables, out);
}